// Round 16
// baseline (308.684 us; speedup 1.0000x reference)
//
#include <hip/hip_runtime.h>

typedef __bf16 bf16x8 __attribute__((ext_vector_type(8)));
typedef float f32x4 __attribute__((ext_vector_type(4)));
typedef int v8i __attribute__((ext_vector_type(8)));

__device__ __forceinline__ unsigned short f2bf(float f) {
    union { float f; unsigned u; } v; v.f = f;
    unsigned u = v.u;
    return (unsigned short)((u + 0x7FFFu + ((u >> 16) & 1u)) >> 16);
}
__device__ __forceinline__ float bf2f(unsigned short h) {
    union { unsigned u; float f; } v; v.u = ((unsigned)h) << 16;
    return v.f;
}
__device__ __forceinline__ bf16x8 ld8(const unsigned short* p) {
    union { uint4 u; bf16x8 b; } cv;
    cv.u = *(const uint4*)p;
    return cv.b;
}
__device__ __forceinline__ float sigmoidf_(float x) {
    return __builtin_amdgcn_rcpf(1.0f + __expf(-x));
}
__device__ __forceinline__ float tanhf_(float x) {
    float xc = fminf(fmaxf(x, -15.0f), 15.0f);
    float e = __expf(-2.0f * xc);
    return (1.0f - e) * __builtin_amdgcn_rcpf(1.0f + e);
}
__device__ __forceinline__ void gl_lds16(const void* g, void* l) {
    __builtin_amdgcn_global_load_lds(
        (const __attribute__((address_space(1))) void*)g,
        (__attribute__((address_space(3))) void*)l, 16, 0, 0);
}

// ---------------- prep: transpose cemb_W, bias sum, W_hh -> fp8 e4m3 x16 -----
__global__ void k_prep(const float* __restrict__ cemb_W,
                       const float* __restrict__ b_ih, const float* __restrict__ b_hh,
                       const float* __restrict__ W_hh,
                       float* __restrict__ cWT, float* __restrict__ bsum,
                       unsigned char* __restrict__ Wq8) {
    int i = blockIdx.x * blockDim.x + threadIdx.x;
    int stride = gridDim.x * blockDim.x;
    const int TOT = 32768 + 1024 + 262144;
    for (; i < TOT; i += stride) {
        if (i < 32768) {
            int idx = i >> 8, e = i & 255;
            cWT[idx * 256 + e] = cemb_W[e * 128 + idx];   // cWT[i][e] = cemb_W[e][i]
        } else if (i < 33792) {
            int g = i - 32768;
            bsum[g] = b_ih[g] + b_hh[g];
        } else {
            int j = i - 33792;
            // scale x16 moves N(0,0.02) weights out of e4m3 subnormal floor
            unsigned p = __builtin_amdgcn_cvt_pk_fp8_f32(W_hh[j] * 16.0f, 0.0f, 0, false);
            Wq8[j] = (unsigned char)p;
        }
    }
}

// ---------------- build A_in = [xemb * Cct, onehots] (bf16, rows m = t*128+b) --
__global__ __launch_bounds__(128) void k_build_in(
    const int* __restrict__ c, const int* __restrict__ r,
    const int* __restrict__ rgap, const int* __restrict__ sgap, const int* __restrict__ pcount,
    const float* __restrict__ E, const float* __restrict__ cWT,
    unsigned short* __restrict__ A) {
    int m = blockIdx.x;
    int b = m & 127, t = m >> 7;
    int src = b * 200 + t;
    int x = c[src] + 1024 * r[src];
    int ra = rgap[src], sa = 32 + sgap[src], pa = 64 + pcount[src];
    int e = threadIdx.x;
#pragma unroll
    for (int j = 0; j < 2; ++j) {
        int ee = e + j * 128;
        float cc = cWT[ra * 256 + ee] + cWT[sa * 256 + ee] + cWT[pa * 256 + ee];
        A[(long)m * 384 + ee] = f2bf(E[(long)x * 256 + ee] * cc);
    }
    A[(long)m * 384 + 256 + e] =
        (e == ra || e == sa || e == pa) ? (unsigned short)0x3F80 : (unsigned short)0;
}

// ---------------- build A_out = [h * Cct_shft, onehots] ----------------------
__global__ __launch_bounds__(128) void k_build_out(
    const int* __restrict__ rgap, const int* __restrict__ sgap, const int* __restrict__ pcount,
    const unsigned short* __restrict__ h_all, const float* __restrict__ cWT,
    unsigned short* __restrict__ A) {
    int m = blockIdx.x;
    int b = m & 127, t = m >> 7;
    int src = b * 200 + t;
    int ra = rgap[src], sa = 32 + sgap[src], pa = 64 + pcount[src];
    int e = threadIdx.x;
#pragma unroll
    for (int j = 0; j < 2; ++j) {
        int ee = e + j * 128;
        float cc = cWT[ra * 256 + ee] + cWT[sa * 256 + ee] + cWT[pa * 256 + ee];
        float v = bf2f(h_all[(long)m * 256 + ee]);
        A[(long)m * 384 + ee] = f2bf(v * cc);
    }
    A[(long)m * 384 + 256 + e] =
        (e == ra || e == sa || e == pa) ? (unsigned short)0x3F80 : (unsigned short)0;
}

// ---------------- GEMM: C[M,1024] = A[M,384](bf16) @ Bw[1024,384](f32)^T -----
// A tile staged via global_load_lds width=16 (LDS byte off = tid*16: linear
// in lane -> wave-uniform base + lane*16, the m97-proven pattern).
// B tile register-staged f32 -> bf16 (unchanged from R14).
// EPI==0: bf16 xg gate-interleaved; EPI==1: sigmoid f32 remapped to [B,T,V].
template<int EPI>
__global__ __launch_bounds__(256) void k_gemm(
    const unsigned short* __restrict__ A,
    const float* __restrict__ Bw,
    const float* __restrict__ bias,
    unsigned short* __restrict__ obf,
    float* __restrict__ of) {
    __shared__ unsigned short As[128 * 32];
    __shared__ unsigned short Bs[128 * 32];
    const int m0 = blockIdx.x * 128, n0 = blockIdx.y * 128;
    const int tid = threadIdx.x;
    const int wave = tid >> 6, lane = tid & 63;
    const int wm = wave >> 1, wn = wave & 1;
    const int n = lane & 15, q = lane >> 4;
    const int rrA = tid >> 2, ccA = (tid & 3) * 8;
    f32x4 acc[4][4] = {};
    for (int ks = 0; ks < 12; ++ks) {
        __syncthreads();
        {   // A tile: async global->LDS, 2 x 16B per thread
            const unsigned short* gA = A + (long)(m0 + rrA) * 384 + ks * 32 + ccA;
            gl_lds16(gA, &As[rrA * 32 + ccA]);
            gl_lds16(gA + 64 * 384, &As[(rrA + 64) * 32 + ccA]);
        }
        {   // B tile: f32 -> bf16 register staging (R14-proven)
            int rr = tid >> 3, cc = (tid & 7) * 4;
#pragma unroll
            for (int j = 0; j < 4; ++j) {
                int row = j * 32 + rr;
                float4 f = *(const float4*)(Bw + (long)(n0 + row) * 384 + ks * 32 + cc);
                ushort4 h;
                h.x = f2bf(f.x); h.y = f2bf(f.y); h.z = f2bf(f.z); h.w = f2bf(f.w);
                *(ushort4*)(&Bs[row * 32 + cc]) = h;
            }
        }
        __syncthreads();
        bf16x8 af[4], bfr[4];
#pragma unroll
        for (int mt = 0; mt < 4; ++mt)
            af[mt] = ld8(&As[(wm * 64 + mt * 16 + n) * 32 + q * 8]);
#pragma unroll
        for (int nt = 0; nt < 4; ++nt)
            bfr[nt] = ld8(&Bs[(wn * 64 + nt * 16 + n) * 32 + q * 8]);
#pragma unroll
        for (int mt = 0; mt < 4; ++mt)
#pragma unroll
            for (int nt = 0; nt < 4; ++nt)
                acc[mt][nt] = __builtin_amdgcn_mfma_f32_16x16x32_bf16(
                    af[mt], bfr[nt], acc[mt][nt], 0, 0, 0);
    }
#pragma unroll
    for (int mt = 0; mt < 4; ++mt) {
#pragma unroll
        for (int nt = 0; nt < 4; ++nt) {
            int col = n0 + wn * 64 + nt * 16 + n;
            float bv = bias[col];
#pragma unroll
            for (int rg = 0; rg < 4; ++rg) {
                int row = m0 + wm * 64 + mt * 16 + q * 4 + rg;
                float v = acc[mt][nt][rg] + bv;
                if (EPI == 0) {
                    obf[(long)row * 1024 + (col & 255) * 4 + (col >> 8)] = f2bf(v);
                } else {
                    int bb = row & 127, tt = row >> 7;
                    of[((long)bb * 200 + tt) * 1024 + col] = sigmoidf_(v);
                }
            }
        }
    }
}

// ---- explicit-AGPR weight residency (R9 idiom x R10 K=128 layout) -----------
#define LDW8(R0, R1, p)                                                     \
    asm volatile("global_load_dwordx4 a[" R0 "], %0, off\n\t"               \
                 "global_load_dwordx4 a[" R1 "], %0, off offset:16"         \
                 :: "v"(p) : "memory")
#define MFMA8(RR, accv, hfv)                                                \
    asm volatile("v_mfma_f32_16x16x128_f8f6f4 %0, %1, a[" RR "], %0"        \
                 : "+v"(accv) : "v"(hfv))

// ---------------- LSTM: 128 WGs x 1 batch row x 8 waves, 2 waves/SIMD --------
// EXACT R14 version (proven 157 us, absmax 0.0039). K=128 fp8 MFMA, weights
// in explicitly numbered AGPRs a[0:127] loaded once by asm global_load.
__global__ __launch_bounds__(512, 2) void k_lstm(
    const unsigned short* __restrict__ xg,   // [200*128][256][4] bf16 gate-interleaved
    const unsigned char* __restrict__ Wq8,   // [1024][256] fp8 e4m3 (x16)
    unsigned short* __restrict__ h_all) {    // [200*128][256] bf16
    __shared__ __align__(32) unsigned char hb8[2][288];  // h fp8 (1 row), dbuf

    const int tid = threadIdx.x;
    const int w = tid >> 6, lane = tid & 63;
    const int n = lane & 15, q = lane >> 4;
    const int b0 = blockIdx.x;               // this WG's batch row
    const int ug = q & 1;                    // lane's unit-group within the wave

    // anchor: force agpr_count = 128 in kernel metadata
    asm volatile("" ::: "a0", "a31", "a63", "a95", "a127");

    // ---- weights: 8 tiles (tg = ug2*4+g) x 2 k-halves -> a[(tg*2+kh)*8 .. +7]
    const int cbase = w * 32 + n;
    const int qoff = q * 32;
#define WSRC(G, UG2, KH) (Wq8 + (((G) * 256 + cbase + (UG2) * 16) << 8) + (KH) * 128 + qoff)
    LDW8("0:3",     "4:7",     WSRC(0, 0, 0));
    LDW8("8:11",    "12:15",   WSRC(0, 0, 1));
    LDW8("16:19",   "20:23",   WSRC(1, 0, 0));
    LDW8("24:27",   "28:31",   WSRC(1, 0, 1));
    LDW8("32:35",   "36:39",   WSRC(2, 0, 0));
    LDW8("40:43",   "44:47",   WSRC(2, 0, 1));
    LDW8("48:51",   "52:55",   WSRC(3, 0, 0));
    LDW8("56:59",   "60:63",   WSRC(3, 0, 1));
    LDW8("64:67",   "68:71",   WSRC(0, 1, 0));
    LDW8("72:75",   "76:79",   WSRC(0, 1, 1));
    LDW8("80:83",   "84:87",   WSRC(1, 1, 0));
    LDW8("88:91",   "92:95",   WSRC(1, 1, 1));
    LDW8("96:99",   "100:103", WSRC(2, 1, 0));
    LDW8("104:107", "108:111", WSRC(2, 1, 1));
    LDW8("112:115", "116:119", WSRC(3, 1, 0));
    LDW8("120:123", "124:127", WSRC(3, 1, 1));
#undef WSRC
    asm volatile("s_waitcnt vmcnt(0)" ::: "memory");
    __builtin_amdgcn_sched_barrier(0);

    for (int i = tid; i < 288; i += 512) { hb8[0][i] = 0; hb8[1][i] = 0; }

    const int u = w * 32 + ug * 16 + n;      // this lane's hidden unit
    const unsigned short* xgp = xg + (long)b0 * 1024 + u * 4;   // += 131072 per t
    unsigned short* hap = h_all + (long)b0 * 256 + u;           // += 32768 per t
    const bool writer = (q < 2);             // one writer per unit

    float cs = 0.f;
    __syncthreads();

    for (int t = 0; t < 200; ++t) {
        const int cur = t & 1, nxt = cur ^ 1;

        // xg load issued now, consumed after the MFMA phase (latency hidden)
        uint2 xv = *(const uint2*)xgp;
        xgp += 131072;

        // h fragments: k-half 0 and 1 (row-replicated -> LDS broadcast)
        v8i hf0 = *(const v8i*)(&hb8[cur][q * 32]);
        v8i hf1 = *(const v8i*)(&hb8[cur][128 + q * 32]);

        // gates: 8 tiles x (2 x K=128), weights from explicit AGPRs
        f32x4 acc0 = {}, acc1 = {}, acc2 = {}, acc3 = {};
        f32x4 acc4 = {}, acc5 = {}, acc6 = {}, acc7 = {};
        MFMA8("0:7",     acc0, hf0); MFMA8("8:15",    acc0, hf1);
        MFMA8("16:23",   acc1, hf0); MFMA8("24:31",   acc1, hf1);
        MFMA8("32:39",   acc2, hf0); MFMA8("40:47",   acc2, hf1);
        MFMA8("48:55",   acc3, hf0); MFMA8("56:63",   acc3, hf1);
        MFMA8("64:71",   acc4, hf0); MFMA8("72:79",   acc4, hf1);
        MFMA8("80:87",   acc5, hf0); MFMA8("88:95",   acc5, hf1);
        MFMA8("96:103",  acc6, hf0); MFMA8("104:111", acc6, hf1);
        MFMA8("112:119", acc7, hf0); MFMA8("120:127", acc7, hf1);

        f32x4 vg0 = ug ? acc4 : acc0;
        f32x4 vg1 = ug ? acc5 : acc1;
        f32x4 vg2 = ug ? acc6 : acc2;
        f32x4 vg3 = ug ? acc7 : acc3;

        // ---- elementwise LSTM update (replicated rows identical -> [0])
        const float S = 1.0f / 256.0f;  // undo x16 * x16 operand scaling (exact)
        {
            float iv = vg0[0] * S + bf2f((unsigned short)(xv.x & 0xFFFFu));
            float fv = vg1[0] * S + bf2f((unsigned short)(xv.x >> 16));
            float gg = vg2[0] * S + bf2f((unsigned short)(xv.y & 0xFFFFu));
            float ov = vg3[0] * S + bf2f((unsigned short)(xv.y >> 16));
            float cn = sigmoidf_(fv) * cs + sigmoidf_(iv) * tanhf_(gg);
            float hv = sigmoidf_(ov) * tanhf_(cn);
            cs = cn;
            if (writer) {
                hap[0] = f2bf(hv);
                unsigned p8 = __builtin_amdgcn_cvt_pk_fp8_f32(hv * 16.0f, 0.0f, 0, false);
                hb8[nxt][u] = (unsigned char)p8;
            }
        }
        hap += 32768;
        __syncthreads();
    }
}

extern "C" void kernel_launch(void* const* d_in, const int* in_sizes, int n_in,
                              void* d_out, int out_size, void* d_ws, size_t ws_size,
                              hipStream_t stream) {
    const int* c        = (const int*)d_in[0];
    const int* r        = (const int*)d_in[1];
    const int* rgap     = (const int*)d_in[2];
    const int* sgap     = (const int*)d_in[3];
    const int* pcount   = (const int*)d_in[4];
    const int* s_rgap   = (const int*)d_in[5];
    const int* s_sgap   = (const int*)d_in[6];
    const int* s_pcount = (const int*)d_in[7];
    const float* E      = (const float*)d_in[8];
    const float* cemb_W = (const float*)d_in[9];
    const float* W_ih   = (const float*)d_in[10];
    const float* W_hh   = (const float*)d_in[11];
    const float* b_ih   = (const float*)d_in[12];
    const float* b_hh   = (const float*)d_in[13];
    const float* out_W  = (const float*)d_in[14];
    const float* out_b  = (const float*)d_in[15];

    char* ws = (char*)d_ws;
    float* cWT            = (float*)(ws);                       // 131072 B
    float* bsum           = (float*)(ws + 131072);              // 4096 B
    unsigned char* Wq8    = (unsigned char*)(ws + 135168);      // 262144 B
    unsigned short* h_all = (unsigned short*)(ws + 397312);     // 13107200 B
    unsigned short* Abuf  = (unsigned short*)(ws + 13504512);   // 19660800 B
    unsigned short* xg    = (unsigned short*)(ws + 33165312);   // 52428800 B

    k_prep<<<256, 256, 0, stream>>>(cemb_W, b_ih, b_hh, W_hh, cWT, bsum, Wq8);
    k_build_in<<<25600, 128, 0, stream>>>(c, r, rgap, sgap, pcount, E, cWT, Abuf);
    k_gemm<0><<<dim3(200, 8), 256, 0, stream>>>(Abuf, W_ih, bsum, xg, nullptr);
    k_lstm<<<128, 512, 0, stream>>>(xg, Wq8, h_all);
    k_build_out<<<25600, 128, 0, stream>>>(s_rgap, s_sgap, s_pcount, h_all, cWT, Abuf);
    k_gemm<1><<<dim3(200, 8), 256, 0, stream>>>(Abuf, out_W, out_b, nullptr, (float*)d_out);
}

// Round 19
// 288.676 us; speedup vs baseline: 1.0693x; 1.0693x over previous
//
#include <hip/hip_runtime.h>

typedef __bf16 bf16x8 __attribute__((ext_vector_type(8)));
typedef float f32x4 __attribute__((ext_vector_type(4)));
typedef int v8i __attribute__((ext_vector_type(8)));

__device__ __forceinline__ unsigned short f2bf(float f) {
    union { float f; unsigned u; } v; v.f = f;
    unsigned u = v.u;
    return (unsigned short)((u + 0x7FFFu + ((u >> 16) & 1u)) >> 16);
}
__device__ __forceinline__ float bf2f(unsigned short h) {
    union { unsigned u; float f; } v; v.u = ((unsigned)h) << 16;
    return v.f;
}
__device__ __forceinline__ bf16x8 ld8(const unsigned short* p) {
    union { uint4 u; bf16x8 b; } cv;
    cv.u = *(const uint4*)p;
    return cv.b;
}
__device__ __forceinline__ float sigmoidf_(float x) {
    return __builtin_amdgcn_rcpf(1.0f + __expf(-x));
}
__device__ __forceinline__ float tanhf_(float x) {
    float xc = fminf(fmaxf(x, -15.0f), 15.0f);
    float e = __expf(-2.0f * xc);
    return (1.0f - e) * __builtin_amdgcn_rcpf(1.0f + e);
}
__device__ __forceinline__ void gl_lds16(const void* g, void* l) {
    __builtin_amdgcn_global_load_lds(
        (const __attribute__((address_space(1))) void*)g,
        (__attribute__((address_space(3))) void*)l, 16, 0, 0);
}

// ---- prep: cemb_W^T, bias sum, W_hh -> fp8 x16, W_ih -> bf16 (into h_all slab)
__global__ void k_prep(const float* __restrict__ cemb_W,
                       const float* __restrict__ b_ih, const float* __restrict__ b_hh,
                       const float* __restrict__ W_hh, const float* __restrict__ W_ih,
                       float* __restrict__ cWT, float* __restrict__ bsum,
                       unsigned char* __restrict__ Wq8,
                       unsigned short* __restrict__ Wihb) {
    int i = blockIdx.x * blockDim.x + threadIdx.x;
    int stride = gridDim.x * blockDim.x;
    const int TOT = 32768 + 1024 + 262144 + 393216;
    for (; i < TOT; i += stride) {
        if (i < 32768) {
            int idx = i >> 8, e = i & 255;
            cWT[idx * 256 + e] = cemb_W[e * 128 + idx];   // cWT[i][e] = cemb_W[e][i]
        } else if (i < 33792) {
            int g = i - 32768;
            bsum[g] = b_ih[g] + b_hh[g];
        } else if (i < 296960) {
            int j = i - 33792;
            // scale x16 moves N(0,0.02) weights out of e4m3 subnormal floor
            unsigned p = __builtin_amdgcn_cvt_pk_fp8_f32(W_hh[j] * 16.0f, 0.0f, 0, false);
            Wq8[j] = (unsigned char)p;
        } else {
            int j = i - 296960;
            Wihb[j] = f2bf(W_ih[j]);
        }
    }
}

// ---- out_W -> bf16 into the xg slab (xg is dead after k_lstm) ---------------
__global__ void k_conv_outw(const float* __restrict__ out_W,
                            unsigned short* __restrict__ Woutb) {
    int i = blockIdx.x * blockDim.x + threadIdx.x;
    int stride = gridDim.x * blockDim.x;
    for (; i < 393216; i += stride) Woutb[i] = f2bf(out_W[i]);
}

// ---------------- build A_in = [xemb * Cct, onehots] (bf16, rows m = t*128+b) --
__global__ __launch_bounds__(128) void k_build_in(
    const int* __restrict__ c, const int* __restrict__ r,
    const int* __restrict__ rgap, const int* __restrict__ sgap, const int* __restrict__ pcount,
    const float* __restrict__ E, const float* __restrict__ cWT,
    unsigned short* __restrict__ A) {
    int m = blockIdx.x;
    int b = m & 127, t = m >> 7;
    int src = b * 200 + t;
    int x = c[src] + 1024 * r[src];
    int ra = rgap[src], sa = 32 + sgap[src], pa = 64 + pcount[src];
    int e = threadIdx.x;
#pragma unroll
    for (int j = 0; j < 2; ++j) {
        int ee = e + j * 128;
        float cc = cWT[ra * 256 + ee] + cWT[sa * 256 + ee] + cWT[pa * 256 + ee];
        A[(long)m * 384 + ee] = f2bf(E[(long)x * 256 + ee] * cc);
    }
    A[(long)m * 384 + 256 + e] =
        (e == ra || e == sa || e == pa) ? (unsigned short)0x3F80 : (unsigned short)0;
}

// ---------------- build A_out = [h * Cct_shft, onehots] ----------------------
__global__ __launch_bounds__(128) void k_build_out(
    const int* __restrict__ rgap, const int* __restrict__ sgap, const int* __restrict__ pcount,
    const unsigned short* __restrict__ h_all, const float* __restrict__ cWT,
    unsigned short* __restrict__ A) {
    int m = blockIdx.x;
    int b = m & 127, t = m >> 7;
    int src = b * 200 + t;
    int ra = rgap[src], sa = 32 + sgap[src], pa = 64 + pcount[src];
    int e = threadIdx.x;
#pragma unroll
    for (int j = 0; j < 2; ++j) {
        int ee = e + j * 128;
        float cc = cWT[ra * 256 + ee] + cWT[sa * 256 + ee] + cWT[pa * 256 + ee];
        float v = bf2f(h_all[(long)m * 256 + ee]);
        A[(long)m * 384 + ee] = f2bf(v * cc);
    }
    A[(long)m * 384 + 256 + e] =
        (e == ra || e == sa || e == pa) ? (unsigned short)0x3F80 : (unsigned short)0;
}

// ---------------- GEMM: C[M,1024] = A[M,384](bf16) @ Bw[1024,384](bf16)^T ----
// BOTH tiles staged via global_load_lds width=16 (linear-in-tid LDS map,
// verified safe for A in R16). EPI 0: bf16 xg gate-interleaved store;
// EPI 1: sigmoid, f32, remapped to [B,T,V].
template<int EPI>
__global__ __launch_bounds__(256) void k_gemm(
    const unsigned short* __restrict__ A,
    const unsigned short* __restrict__ Bw,
    const float* __restrict__ bias,
    unsigned short* __restrict__ obf,
    float* __restrict__ of) {
    __shared__ unsigned short As[128 * 32];
    __shared__ unsigned short Bs[128 * 32];
    const int m0 = blockIdx.x * 128, n0 = blockIdx.y * 128;
    const int tid = threadIdx.x;
    const int wave = tid >> 6, lane = tid & 63;
    const int wm = wave >> 1, wn = wave & 1;
    const int n = lane & 15, q = lane >> 4;
    const int rrA = tid >> 2, ccA = (tid & 3) * 8;
    f32x4 acc[4][4] = {};
    for (int ks = 0; ks < 12; ++ks) {
        __syncthreads();
        {   // A + B tiles: async global->LDS, 4 x 16B per thread
            const unsigned short* gA = A + (long)(m0 + rrA) * 384 + ks * 32 + ccA;
            gl_lds16(gA, &As[rrA * 32 + ccA]);
            gl_lds16(gA + 64 * 384, &As[(rrA + 64) * 32 + ccA]);
            const unsigned short* gB = Bw + (long)(n0 + rrA) * 384 + ks * 32 + ccA;
            gl_lds16(gB, &Bs[rrA * 32 + ccA]);
            gl_lds16(gB + 64 * 384, &Bs[(rrA + 64) * 32 + ccA]);
        }
        __syncthreads();
        bf16x8 af[4], bfr[4];
#pragma unroll
        for (int mt = 0; mt < 4; ++mt)
            af[mt] = ld8(&As[(wm * 64 + mt * 16 + n) * 32 + q * 8]);
#pragma unroll
        for (int nt = 0; nt < 4; ++nt)
            bfr[nt] = ld8(&Bs[(wn * 64 + nt * 16 + n) * 32 + q * 8]);
#pragma unroll
        for (int mt = 0; mt < 4; ++mt)
#pragma unroll
            for (int nt = 0; nt < 4; ++nt)
                acc[mt][nt] = __builtin_amdgcn_mfma_f32_16x16x32_bf16(
                    af[mt], bfr[nt], acc[mt][nt], 0, 0, 0);
    }
#pragma unroll
    for (int mt = 0; mt < 4; ++mt) {
#pragma unroll
        for (int nt = 0; nt < 4; ++nt) {
            int col = n0 + wn * 64 + nt * 16 + n;
            float bv = bias[col];
#pragma unroll
            for (int rg = 0; rg < 4; ++rg) {
                int row = m0 + wm * 64 + mt * 16 + q * 4 + rg;
                float v = acc[mt][nt][rg] + bv;
                if (EPI == 0) {
                    obf[(long)row * 1024 + (col & 255) * 4 + (col >> 8)] = f2bf(v);
                } else {
                    int bb = row & 127, tt = row >> 7;
                    of[((long)bb * 200 + tt) * 1024 + col] = sigmoidf_(v);
                }
            }
        }
    }
}

// ---- explicit-AGPR weight residency (R9 idiom x R10 K=128 layout) -----------
#define LDW8(R0, R1, p)                                                     \
    asm volatile("global_load_dwordx4 a[" R0 "], %0, off\n\t"               \
                 "global_load_dwordx4 a[" R1 "], %0, off offset:16"         \
                 :: "v"(p) : "memory")
#define MFMA8(RR, accv, hfv)                                                \
    asm volatile("v_mfma_f32_16x16x128_f8f6f4 %0, %1, a[" RR "], %0"        \
                 : "+v"(accv) : "v"(hfv))

// ---------------- LSTM: 128 WGs x 1 batch row x 8 waves, 2 waves/SIMD --------
// EXACT R14/R16 version (proven 157 us, absmax 0.0039). K=128 fp8 MFMA,
// weights in explicitly numbered AGPRs a[0:127] loaded once by asm global_load.
__global__ __launch_bounds__(512, 2) void k_lstm(
    const unsigned short* __restrict__ xg,   // [200*128][256][4] bf16 gate-interleaved
    const unsigned char* __restrict__ Wq8,   // [1024][256] fp8 e4m3 (x16)
    unsigned short* __restrict__ h_all) {    // [200*128][256] bf16
    __shared__ __align__(32) unsigned char hb8[2][288];  // h fp8 (1 row), dbuf

    const int tid = threadIdx.x;
    const int w = tid >> 6, lane = tid & 63;
    const int n = lane & 15, q = lane >> 4;
    const int b0 = blockIdx.x;               // this WG's batch row
    const int ug = q & 1;                    // lane's unit-group within the wave

    // anchor: force agpr_count = 128 in kernel metadata
    asm volatile("" ::: "a0", "a31", "a63", "a95", "a127");

    // ---- weights: 8 tiles (tg = ug2*4+g) x 2 k-halves -> a[(tg*2+kh)*8 .. +7]
    const int cbase = w * 32 + n;
    const int qoff = q * 32;
#define WSRC(G, UG2, KH) (Wq8 + (((G) * 256 + cbase + (UG2) * 16) << 8) + (KH) * 128 + qoff)
    LDW8("0:3",     "4:7",     WSRC(0, 0, 0));
    LDW8("8:11",    "12:15",   WSRC(0, 0, 1));
    LDW8("16:19",   "20:23",   WSRC(1, 0, 0));
    LDW8("24:27",   "28:31",   WSRC(1, 0, 1));
    LDW8("32:35",   "36:39",   WSRC(2, 0, 0));
    LDW8("40:43",   "44:47",   WSRC(2, 0, 1));
    LDW8("48:51",   "52:55",   WSRC(3, 0, 0));
    LDW8("56:59",   "60:63",   WSRC(3, 0, 1));
    LDW8("64:67",   "68:71",   WSRC(0, 1, 0));
    LDW8("72:75",   "76:79",   WSRC(0, 1, 1));
    LDW8("80:83",   "84:87",   WSRC(1, 1, 0));
    LDW8("88:91",   "92:95",   WSRC(1, 1, 1));
    LDW8("96:99",   "100:103", WSRC(2, 1, 0));
    LDW8("104:107", "108:111", WSRC(2, 1, 1));
    LDW8("112:115", "116:119", WSRC(3, 1, 0));
    LDW8("120:123", "124:127", WSRC(3, 1, 1));
#undef WSRC
    asm volatile("s_waitcnt vmcnt(0)" ::: "memory");
    __builtin_amdgcn_sched_barrier(0);

    for (int i = tid; i < 288; i += 512) { hb8[0][i] = 0; hb8[1][i] = 0; }

    const int u = w * 32 + ug * 16 + n;      // this lane's hidden unit
    const unsigned short* xgp = xg + (long)b0 * 1024 + u * 4;   // += 131072 per t
    unsigned short* hap = h_all + (long)b0 * 256 + u;           // += 32768 per t
    const bool writer = (q < 2);             // one writer per unit

    float cs = 0.f;
    __syncthreads();

    for (int t = 0; t < 200; ++t) {
        const int cur = t & 1, nxt = cur ^ 1;

        // xg load issued now, consumed after the MFMA phase (latency hidden)
        uint2 xv = *(const uint2*)xgp;
        xgp += 131072;

        // h fragments: k-half 0 and 1 (row-replicated -> LDS broadcast)
        v8i hf0 = *(const v8i*)(&hb8[cur][q * 32]);
        v8i hf1 = *(const v8i*)(&hb8[cur][128 + q * 32]);

        // gates: 8 tiles x (2 x K=128), weights from explicit AGPRs
        f32x4 acc0 = {}, acc1 = {}, acc2 = {}, acc3 = {};
        f32x4 acc4 = {}, acc5 = {}, acc6 = {}, acc7 = {};
        MFMA8("0:7",     acc0, hf0); MFMA8("8:15",    acc0, hf1);
        MFMA8("16:23",   acc1, hf0); MFMA8("24:31",   acc1, hf1);
        MFMA8("32:39",   acc2, hf0); MFMA8("40:47",   acc2, hf1);
        MFMA8("48:55",   acc3, hf0); MFMA8("56:63",   acc3, hf1);
        MFMA8("64:71",   acc4, hf0); MFMA8("72:79",   acc4, hf1);
        MFMA8("80:87",   acc5, hf0); MFMA8("88:95",   acc5, hf1);
        MFMA8("96:103",  acc6, hf0); MFMA8("104:111", acc6, hf1);
        MFMA8("112:119", acc7, hf0); MFMA8("120:127", acc7, hf1);

        f32x4 vg0 = ug ? acc4 : acc0;
        f32x4 vg1 = ug ? acc5 : acc1;
        f32x4 vg2 = ug ? acc6 : acc2;
        f32x4 vg3 = ug ? acc7 : acc3;

        // ---- elementwise LSTM update (replicated rows identical -> use [0])
        const float S = 1.0f / 256.0f;  // undo x16 * x16 operand scaling (exact)
        {
            float iv = vg0[0] * S + bf2f((unsigned short)(xv.x & 0xFFFFu));
            float fv = vg1[0] * S + bf2f((unsigned short)(xv.x >> 16));
            float gg = vg2[0] * S + bf2f((unsigned short)(xv.y & 0xFFFFu));
            float ov = vg3[0] * S + bf2f((unsigned short)(xv.y >> 16));
            float cn = sigmoidf_(fv) * cs + sigmoidf_(iv) * tanhf_(gg);
            float hv = sigmoidf_(ov) * tanhf_(cn);
            cs = cn;
            if (writer) {
                hap[0] = f2bf(hv);
                unsigned p8 = __builtin_amdgcn_cvt_pk_fp8_f32(hv * 16.0f, 0.0f, 0, false);
                hb8[nxt][u] = (unsigned char)p8;
            }
        }
        hap += 32768;
        __syncthreads();
    }
}

extern "C" void kernel_launch(void* const* d_in, const int* in_sizes, int n_in,
                              void* d_out, int out_size, void* d_ws, size_t ws_size,
                              hipStream_t stream) {
    const int* c        = (const int*)d_in[0];
    const int* r        = (const int*)d_in[1];
    const int* rgap     = (const int*)d_in[2];
    const int* sgap     = (const int*)d_in[3];
    const int* pcount   = (const int*)d_in[4];
    const int* s_rgap   = (const int*)d_in[5];
    const int* s_sgap   = (const int*)d_in[6];
    const int* s_pcount = (const int*)d_in[7];
    const float* E      = (const float*)d_in[8];
    const float* cemb_W = (const float*)d_in[9];
    const float* W_ih   = (const float*)d_in[10];
    const float* W_hh   = (const float*)d_in[11];
    const float* b_ih   = (const float*)d_in[12];
    const float* b_hh   = (const float*)d_in[13];
    const float* out_W  = (const float*)d_in[14];
    const float* out_b  = (const float*)d_in[15];

    char* ws = (char*)d_ws;
    float* cWT            = (float*)(ws);                       // 131072 B
    float* bsum           = (float*)(ws + 131072);              // 4096 B
    unsigned char* Wq8    = (unsigned char*)(ws + 135168);      // 262144 B
    unsigned short* h_all = (unsigned short*)(ws + 397312);     // 13107200 B
    unsigned short* Abuf  = (unsigned short*)(ws + 13504512);   // 19660800 B
    unsigned short* xg    = (unsigned short*)(ws + 33165312);   // 52428800 B
    // aliases into DEAD regions (no ws growth):
    unsigned short* Wihb  = h_all;  // prep writes, gemm0 reads; k_lstm clobbers later
    unsigned short* Woutb = xg;     // k_conv_outw writes AFTER k_lstm (xg dead)

    k_prep<<<256, 256, 0, stream>>>(cemb_W, b_ih, b_hh, W_hh, W_ih,
                                    cWT, bsum, Wq8, Wihb);
    k_build_in<<<25600, 128, 0, stream>>>(c, r, rgap, sgap, pcount, E, cWT, Abuf);
    k_gemm<0><<<dim3(200, 8), 256, 0, stream>>>(Abuf, Wihb, bsum, xg, nullptr);
    k_lstm<<<128, 512, 0, stream>>>(xg, Wq8, h_all);
    k_conv_outw<<<384, 256, 0, stream>>>(out_W, Woutb);
    k_build_out<<<25600, 128, 0, stream>>>(s_rgap, s_sgap, s_pcount, h_all, cWT, Abuf);
    k_gemm<1><<<dim3(200, 8), 256, 0, stream>>>(Abuf, Woutb, out_b, nullptr, (float*)d_out);
}

// Round 20
// 286.608 us; speedup vs baseline: 1.0770x; 1.0072x over previous
//
#include <hip/hip_runtime.h>

typedef __bf16 bf16x8 __attribute__((ext_vector_type(8)));
typedef float f32x4 __attribute__((ext_vector_type(4)));
typedef int v8i __attribute__((ext_vector_type(8)));

__device__ __forceinline__ unsigned short f2bf(float f) {
    union { float f; unsigned u; } v; v.f = f;
    unsigned u = v.u;
    return (unsigned short)((u + 0x7FFFu + ((u >> 16) & 1u)) >> 16);
}
__device__ __forceinline__ float bf2f(unsigned short h) {
    union { unsigned u; float f; } v; v.u = ((unsigned)h) << 16;
    return v.f;
}
__device__ __forceinline__ bf16x8 ld8(const unsigned short* p) {
    union { uint4 u; bf16x8 b; } cv;
    cv.u = *(const uint4*)p;
    return cv.b;
}
__device__ __forceinline__ float sigmoidf_(float x) {
    return __builtin_amdgcn_rcpf(1.0f + __expf(-x));
}
__device__ __forceinline__ float tanhf_(float x) {
    float xc = fminf(fmaxf(x, -15.0f), 15.0f);
    float e = __expf(-2.0f * xc);
    return (1.0f - e) * __builtin_amdgcn_rcpf(1.0f + e);
}
__device__ __forceinline__ void gl_lds16(const void* g, void* l) {
    __builtin_amdgcn_global_load_lds(
        (const __attribute__((address_space(1))) void*)g,
        (__attribute__((address_space(3))) void*)l, 16, 0, 0);
}

// ---- prep: cemb_W^T, bias sum, W_hh -> fp8 x16, W_ih -> bf16 (into h_all slab)
__global__ void k_prep(const float* __restrict__ cemb_W,
                       const float* __restrict__ b_ih, const float* __restrict__ b_hh,
                       const float* __restrict__ W_hh, const float* __restrict__ W_ih,
                       float* __restrict__ cWT, float* __restrict__ bsum,
                       unsigned char* __restrict__ Wq8,
                       unsigned short* __restrict__ Wihb) {
    int i = blockIdx.x * blockDim.x + threadIdx.x;
    int stride = gridDim.x * blockDim.x;
    const int TOT = 32768 + 1024 + 262144 + 393216;
    for (; i < TOT; i += stride) {
        if (i < 32768) {
            int idx = i >> 8, e = i & 255;
            cWT[idx * 256 + e] = cemb_W[e * 128 + idx];   // cWT[i][e] = cemb_W[e][i]
        } else if (i < 33792) {
            int g = i - 32768;
            bsum[g] = b_ih[g] + b_hh[g];
        } else if (i < 296960) {
            int j = i - 33792;
            // scale x16 moves N(0,0.02) weights out of e4m3 subnormal floor
            unsigned p = __builtin_amdgcn_cvt_pk_fp8_f32(W_hh[j] * 16.0f, 0.0f, 0, false);
            Wq8[j] = (unsigned char)p;
        } else {
            int j = i - 296960;
            Wihb[j] = f2bf(W_ih[j]);
        }
    }
}

// ---- out_W -> bf16 into the xg slab (xg is dead after k_lstm) ---------------
__global__ void k_conv_outw(const float* __restrict__ out_W,
                            unsigned short* __restrict__ Woutb) {
    int i = blockIdx.x * blockDim.x + threadIdx.x;
    int stride = gridDim.x * blockDim.x;
    for (; i < 393216; i += stride) Woutb[i] = f2bf(out_W[i]);
}

// ---------------- build A_in = [xemb * Cct, onehots] (bf16, rows m = t*128+b) --
__global__ __launch_bounds__(128) void k_build_in(
    const int* __restrict__ c, const int* __restrict__ r,
    const int* __restrict__ rgap, const int* __restrict__ sgap, const int* __restrict__ pcount,
    const float* __restrict__ E, const float* __restrict__ cWT,
    unsigned short* __restrict__ A) {
    int m = blockIdx.x;
    int b = m & 127, t = m >> 7;
    int src = b * 200 + t;
    int x = c[src] + 1024 * r[src];
    int ra = rgap[src], sa = 32 + sgap[src], pa = 64 + pcount[src];
    int e = threadIdx.x;
#pragma unroll
    for (int j = 0; j < 2; ++j) {
        int ee = e + j * 128;
        float cc = cWT[ra * 256 + ee] + cWT[sa * 256 + ee] + cWT[pa * 256 + ee];
        A[(long)m * 384 + ee] = f2bf(E[(long)x * 256 + ee] * cc);
    }
    A[(long)m * 384 + 256 + e] =
        (e == ra || e == sa || e == pa) ? (unsigned short)0x3F80 : (unsigned short)0;
}

// ---------------- build A_out = [h * Cct_shft, onehots] ----------------------
__global__ __launch_bounds__(128) void k_build_out(
    const int* __restrict__ rgap, const int* __restrict__ sgap, const int* __restrict__ pcount,
    const unsigned short* __restrict__ h_all, const float* __restrict__ cWT,
    unsigned short* __restrict__ A) {
    int m = blockIdx.x;
    int b = m & 127, t = m >> 7;
    int src = b * 200 + t;
    int ra = rgap[src], sa = 32 + sgap[src], pa = 64 + pcount[src];
    int e = threadIdx.x;
#pragma unroll
    for (int j = 0; j < 2; ++j) {
        int ee = e + j * 128;
        float cc = cWT[ra * 256 + ee] + cWT[sa * 256 + ee] + cWT[pa * 256 + ee];
        float v = bf2f(h_all[(long)m * 256 + ee]);
        A[(long)m * 384 + ee] = f2bf(v * cc);
    }
    A[(long)m * 384 + 256 + e] =
        (e == ra || e == sa || e == pa) ? (unsigned short)0x3F80 : (unsigned short)0;
}

// ---------------- GEMM: C[M,1024] = A[M,384](bf16) @ Bw[1024,384](bf16)^T ----
// BOTH tiles staged via global_load_lds width=16 (R19-verified).
// EPI 0: bf16 xg gate-interleaved store; EPI 1: sigmoid f32 to [B,T,V].
template<int EPI>
__global__ __launch_bounds__(256) void k_gemm(
    const unsigned short* __restrict__ A,
    const unsigned short* __restrict__ Bw,
    const float* __restrict__ bias,
    unsigned short* __restrict__ obf,
    float* __restrict__ of) {
    __shared__ unsigned short As[128 * 32];
    __shared__ unsigned short Bs[128 * 32];
    const int m0 = blockIdx.x * 128, n0 = blockIdx.y * 128;
    const int tid = threadIdx.x;
    const int wave = tid >> 6, lane = tid & 63;
    const int wm = wave >> 1, wn = wave & 1;
    const int n = lane & 15, q = lane >> 4;
    const int rrA = tid >> 2, ccA = (tid & 3) * 8;
    f32x4 acc[4][4] = {};
    for (int ks = 0; ks < 12; ++ks) {
        __syncthreads();
        {   // A + B tiles: async global->LDS, 4 x 16B per thread
            const unsigned short* gA = A + (long)(m0 + rrA) * 384 + ks * 32 + ccA;
            gl_lds16(gA, &As[rrA * 32 + ccA]);
            gl_lds16(gA + 64 * 384, &As[(rrA + 64) * 32 + ccA]);
            const unsigned short* gB = Bw + (long)(n0 + rrA) * 384 + ks * 32 + ccA;
            gl_lds16(gB, &Bs[rrA * 32 + ccA]);
            gl_lds16(gB + 64 * 384, &Bs[(rrA + 64) * 32 + ccA]);
        }
        __syncthreads();
        bf16x8 af[4], bfr[4];
#pragma unroll
        for (int mt = 0; mt < 4; ++mt)
            af[mt] = ld8(&As[(wm * 64 + mt * 16 + n) * 32 + q * 8]);
#pragma unroll
        for (int nt = 0; nt < 4; ++nt)
            bfr[nt] = ld8(&Bs[(wn * 64 + nt * 16 + n) * 32 + q * 8]);
#pragma unroll
        for (int mt = 0; mt < 4; ++mt)
#pragma unroll
            for (int nt = 0; nt < 4; ++nt)
                acc[mt][nt] = __builtin_amdgcn_mfma_f32_16x16x32_bf16(
                    af[mt], bfr[nt], acc[mt][nt], 0, 0, 0);
    }
#pragma unroll
    for (int mt = 0; mt < 4; ++mt) {
#pragma unroll
        for (int nt = 0; nt < 4; ++nt) {
            int col = n0 + wn * 64 + nt * 16 + n;
            float bv = bias[col];
#pragma unroll
            for (int rg = 0; rg < 4; ++rg) {
                int row = m0 + wm * 64 + mt * 16 + q * 4 + rg;
                float v = acc[mt][nt][rg] + bv;
                if (EPI == 0) {
                    obf[(long)row * 1024 + (col & 255) * 4 + (col >> 8)] = f2bf(v);
                } else {
                    int bb = row & 127, tt = row >> 7;
                    of[((long)bb * 200 + tt) * 1024 + col] = sigmoidf_(v);
                }
            }
        }
    }
}

// ---- explicit-AGPR weight residency (R9 idiom x R10 K=128 layout) -----------
#define LDW8(R0, R1, p)                                                     \
    asm volatile("global_load_dwordx4 a[" R0 "], %0, off\n\t"               \
                 "global_load_dwordx4 a[" R1 "], %0, off offset:16"         \
                 :: "v"(p) : "memory")
#define MFMA8(RR, accv, hfv)                                                \
    asm volatile("v_mfma_f32_16x16x128_f8f6f4 %0, %1, a[" RR "], %0"        \
                 : "+v"(accv) : "v"(hfv))

// ---------------- LSTM: 128 WGs x 1 batch row x 8 waves, 2 waves/SIMD --------
// R14/R16 core + ONE change: h_all global store DEFERRED by one step, issued
// right after the barrier so it retires under the ~1100-cyc MFMA phase instead
// of stalling the barrier's implicit s_waitcnt vmcnt(0) (m97 asm: __syncthreads
// drains all outstanding stores).
__global__ __launch_bounds__(512, 2) void k_lstm(
    const unsigned short* __restrict__ xg,   // [200*128][256][4] bf16 gate-interleaved
    const unsigned char* __restrict__ Wq8,   // [1024][256] fp8 e4m3 (x16)
    unsigned short* __restrict__ h_all) {    // [200*128][256] bf16
    __shared__ __align__(32) unsigned char hb8[2][288];  // h fp8 (1 row), dbuf

    const int tid = threadIdx.x;
    const int w = tid >> 6, lane = tid & 63;
    const int n = lane & 15, q = lane >> 4;
    const int b0 = blockIdx.x;               // this WG's batch row
    const int ug = q & 1;                    // lane's unit-group within the wave

    // anchor: force agpr_count = 128 in kernel metadata
    asm volatile("" ::: "a0", "a31", "a63", "a95", "a127");

    // ---- weights: 8 tiles (tg = ug2*4+g) x 2 k-halves -> a[(tg*2+kh)*8 .. +7]
    const int cbase = w * 32 + n;
    const int qoff = q * 32;
#define WSRC(G, UG2, KH) (Wq8 + (((G) * 256 + cbase + (UG2) * 16) << 8) + (KH) * 128 + qoff)
    LDW8("0:3",     "4:7",     WSRC(0, 0, 0));
    LDW8("8:11",    "12:15",   WSRC(0, 0, 1));
    LDW8("16:19",   "20:23",   WSRC(1, 0, 0));
    LDW8("24:27",   "28:31",   WSRC(1, 0, 1));
    LDW8("32:35",   "36:39",   WSRC(2, 0, 0));
    LDW8("40:43",   "44:47",   WSRC(2, 0, 1));
    LDW8("48:51",   "52:55",   WSRC(3, 0, 0));
    LDW8("56:59",   "60:63",   WSRC(3, 0, 1));
    LDW8("64:67",   "68:71",   WSRC(0, 1, 0));
    LDW8("72:75",   "76:79",   WSRC(0, 1, 1));
    LDW8("80:83",   "84:87",   WSRC(1, 1, 0));
    LDW8("88:91",   "92:95",   WSRC(1, 1, 1));
    LDW8("96:99",   "100:103", WSRC(2, 1, 0));
    LDW8("104:107", "108:111", WSRC(2, 1, 1));
    LDW8("112:115", "116:119", WSRC(3, 1, 0));
    LDW8("120:123", "124:127", WSRC(3, 1, 1));
#undef WSRC
    asm volatile("s_waitcnt vmcnt(0)" ::: "memory");
    __builtin_amdgcn_sched_barrier(0);

    for (int i = tid; i < 288; i += 512) { hb8[0][i] = 0; hb8[1][i] = 0; }

    const int u = w * 32 + ug * 16 + n;      // this lane's hidden unit
    const unsigned short* xgp = xg + (long)b0 * 1024 + u * 4;   // += 131072 per t
    unsigned short* hap = h_all + (long)b0 * 256 + u;           // step-t slot, advanced on store
    const bool writer = (q < 2);             // one writer per unit

    unsigned short hv_keep = 0;
    float cs = 0.f;
    __syncthreads();

    for (int t = 0; t < 200; ++t) {
        const int cur = t & 1, nxt = cur ^ 1;

        // xg load issued now, consumed after the MFMA phase (latency hidden)
        uint2 xv = *(const uint2*)xgp;
        xgp += 131072;

        // deferred h_all store of step t-1: issued just after the barrier so it
        // retires under the MFMA phase instead of stalling this step's barrier
        if (t && writer) { *hap = hv_keep; hap += 32768; }

        // h fragments: k-half 0 and 1 (row-replicated -> LDS broadcast)
        v8i hf0 = *(const v8i*)(&hb8[cur][q * 32]);
        v8i hf1 = *(const v8i*)(&hb8[cur][128 + q * 32]);

        // gates: 8 tiles x (2 x K=128), weights from explicit AGPRs
        f32x4 acc0 = {}, acc1 = {}, acc2 = {}, acc3 = {};
        f32x4 acc4 = {}, acc5 = {}, acc6 = {}, acc7 = {};
        MFMA8("0:7",     acc0, hf0); MFMA8("8:15",    acc0, hf1);
        MFMA8("16:23",   acc1, hf0); MFMA8("24:31",   acc1, hf1);
        MFMA8("32:39",   acc2, hf0); MFMA8("40:47",   acc2, hf1);
        MFMA8("48:55",   acc3, hf0); MFMA8("56:63",   acc3, hf1);
        MFMA8("64:71",   acc4, hf0); MFMA8("72:79",   acc4, hf1);
        MFMA8("80:87",   acc5, hf0); MFMA8("88:95",   acc5, hf1);
        MFMA8("96:103",  acc6, hf0); MFMA8("104:111", acc6, hf1);
        MFMA8("112:119", acc7, hf0); MFMA8("120:127", acc7, hf1);

        f32x4 vg0 = ug ? acc4 : acc0;
        f32x4 vg1 = ug ? acc5 : acc1;
        f32x4 vg2 = ug ? acc6 : acc2;
        f32x4 vg3 = ug ? acc7 : acc3;

        // ---- elementwise LSTM update (replicated rows identical -> use [0])
        const float S = 1.0f / 256.0f;  // undo x16 * x16 operand scaling (exact)
        {
            float iv = vg0[0] * S + bf2f((unsigned short)(xv.x & 0xFFFFu));
            float fv = vg1[0] * S + bf2f((unsigned short)(xv.x >> 16));
            float gg = vg2[0] * S + bf2f((unsigned short)(xv.y & 0xFFFFu));
            float ov = vg3[0] * S + bf2f((unsigned short)(xv.y >> 16));
            float cn = sigmoidf_(fv) * cs + sigmoidf_(iv) * tanhf_(gg);
            float hv = sigmoidf_(ov) * tanhf_(cn);
            cs = cn;
            if (writer) {
                unsigned p8 = __builtin_amdgcn_cvt_pk_fp8_f32(hv * 16.0f, 0.0f, 0, false);
                hb8[nxt][u] = (unsigned char)p8;   // LDS: must land before barrier
                hv_keep = f2bf(hv);                // global store deferred to t+1
            }
        }
        __syncthreads();
    }
    if (writer) *hap = hv_keep;  // step-199 h_all store
}

extern "C" void kernel_launch(void* const* d_in, const int* in_sizes, int n_in,
                              void* d_out, int out_size, void* d_ws, size_t ws_size,
                              hipStream_t stream) {
    const int* c        = (const int*)d_in[0];
    const int* r        = (const int*)d_in[1];
    const int* rgap     = (const int*)d_in[2];
    const int* sgap     = (const int*)d_in[3];
    const int* pcount   = (const int*)d_in[4];
    const int* s_rgap   = (const int*)d_in[5];
    const int* s_sgap   = (const int*)d_in[6];
    const int* s_pcount = (const int*)d_in[7];
    const float* E      = (const float*)d_in[8];
    const float* cemb_W = (const float*)d_in[9];
    const float* W_ih   = (const float*)d_in[10];
    const float* W_hh   = (const float*)d_in[11];
    const float* b_ih   = (const float*)d_in[12];
    const float* b_hh   = (const float*)d_in[13];
    const float* out_W  = (const float*)d_in[14];
    const float* out_b  = (const float*)d_in[15];

    char* ws = (char*)d_ws;
    float* cWT            = (float*)(ws);                       // 131072 B
    float* bsum           = (float*)(ws + 131072);              // 4096 B
    unsigned char* Wq8    = (unsigned char*)(ws + 135168);      // 262144 B
    unsigned short* h_all = (unsigned short*)(ws + 397312);     // 13107200 B
    unsigned short* Abuf  = (unsigned short*)(ws + 13504512);   // 19660800 B
    unsigned short* xg    = (unsigned short*)(ws + 33165312);   // 52428800 B
    // aliases into DEAD regions (no ws growth):
    unsigned short* Wihb  = h_all;  // prep writes, gemm0 reads; k_lstm clobbers later
    unsigned short* Woutb = xg;     // k_conv_outw writes AFTER k_lstm (xg dead)

    k_prep<<<256, 256, 0, stream>>>(cemb_W, b_ih, b_hh, W_hh, W_ih,
                                    cWT, bsum, Wq8, Wihb);
    k_build_in<<<25600, 128, 0, stream>>>(c, r, rgap, sgap, pcount, E, cWT, Abuf);
    k_gemm<0><<<dim3(200, 8), 256, 0, stream>>>(Abuf, Wihb, bsum, xg, nullptr);
    k_lstm<<<128, 512, 0, stream>>>(xg, Wq8, h_all);
    k_conv_outw<<<384, 256, 0, stream>>>(out_W, Woutb);
    k_build_out<<<25600, 128, 0, stream>>>(s_rgap, s_sgap, s_pcount, h_all, cWT, Abuf);
    k_gemm<1><<<dim3(200, 8), 256, 0, stream>>>(Abuf, Woutb, out_b, nullptr, (float*)d_out);
}

// Round 21
// 268.100 us; speedup vs baseline: 1.1514x; 1.0690x over previous
//
#include <hip/hip_runtime.h>

typedef __bf16 bf16x8 __attribute__((ext_vector_type(8)));
typedef float f32x4 __attribute__((ext_vector_type(4)));
typedef int v8i __attribute__((ext_vector_type(8)));

__device__ __forceinline__ unsigned short f2bf(float f) {
    union { float f; unsigned u; } v; v.f = f;
    unsigned u = v.u;
    return (unsigned short)((u + 0x7FFFu + ((u >> 16) & 1u)) >> 16);
}
__device__ __forceinline__ float bf2f(unsigned short h) {
    union { unsigned u; float f; } v; v.u = ((unsigned)h) << 16;
    return v.f;
}
__device__ __forceinline__ bf16x8 ld8(const unsigned short* p) {
    union { uint4 u; bf16x8 b; } cv;
    cv.u = *(const uint4*)p;
    return cv.b;
}
__device__ __forceinline__ float sigmoidf_(float x) {
    return __builtin_amdgcn_rcpf(1.0f + __expf(-x));
}
__device__ __forceinline__ float tanhf_(float x) {
    float xc = fminf(fmaxf(x, -15.0f), 15.0f);
    float e = __expf(-2.0f * xc);
    return (1.0f - e) * __builtin_amdgcn_rcpf(1.0f + e);
}
__device__ __forceinline__ void gl_lds16(const void* g, void* l) {
    __builtin_amdgcn_global_load_lds(
        (const __attribute__((address_space(1))) void*)g,
        (__attribute__((address_space(3))) void*)l, 16, 0, 0);
}

// ---- prep: cemb_W^T, bias sum, W_hh -> fp8 x16, W_ih -> bf16 (into h_all slab)
__global__ void k_prep(const float* __restrict__ cemb_W,
                       const float* __restrict__ b_ih, const float* __restrict__ b_hh,
                       const float* __restrict__ W_hh, const float* __restrict__ W_ih,
                       float* __restrict__ cWT, float* __restrict__ bsum,
                       unsigned char* __restrict__ Wq8,
                       unsigned short* __restrict__ Wihb) {
    int i = blockIdx.x * blockDim.x + threadIdx.x;
    int stride = gridDim.x * blockDim.x;
    const int TOT = 32768 + 1024 + 262144 + 393216;
    for (; i < TOT; i += stride) {
        if (i < 32768) {
            int idx = i >> 8, e = i & 255;
            cWT[idx * 256 + e] = cemb_W[e * 128 + idx];   // cWT[i][e] = cemb_W[e][i]
        } else if (i < 33792) {
            int g = i - 32768;
            bsum[g] = b_ih[g] + b_hh[g];
        } else if (i < 296960) {
            int j = i - 33792;
            // scale x16 moves N(0,0.02) weights out of e4m3 subnormal floor
            unsigned p = __builtin_amdgcn_cvt_pk_fp8_f32(W_hh[j] * 16.0f, 0.0f, 0, false);
            Wq8[j] = (unsigned char)p;
        } else {
            int j = i - 296960;
            Wihb[j] = f2bf(W_ih[j]);
        }
    }
}

// ---- out_W -> bf16 into the xg slab (xg is dead after k_lstm) ---------------
__global__ void k_conv_outw(const float* __restrict__ out_W,
                            unsigned short* __restrict__ Woutb) {
    int i = blockIdx.x * blockDim.x + threadIdx.x;
    int stride = gridDim.x * blockDim.x;
    for (; i < 393216; i += stride) Woutb[i] = f2bf(out_W[i]);
}

// ---------------- build A_in = [xemb * Cct, onehots] (bf16, rows m = t*128+b) --
__global__ __launch_bounds__(128) void k_build_in(
    const int* __restrict__ c, const int* __restrict__ r,
    const int* __restrict__ rgap, const int* __restrict__ sgap, const int* __restrict__ pcount,
    const float* __restrict__ E, const float* __restrict__ cWT,
    unsigned short* __restrict__ A) {
    int m = blockIdx.x;
    int b = m & 127, t = m >> 7;
    int src = b * 200 + t;
    int x = c[src] + 1024 * r[src];
    int ra = rgap[src], sa = 32 + sgap[src], pa = 64 + pcount[src];
    int e = threadIdx.x;
#pragma unroll
    for (int j = 0; j < 2; ++j) {
        int ee = e + j * 128;
        float cc = cWT[ra * 256 + ee] + cWT[sa * 256 + ee] + cWT[pa * 256 + ee];
        A[(long)m * 384 + ee] = f2bf(E[(long)x * 256 + ee] * cc);
    }
    A[(long)m * 384 + 256 + e] =
        (e == ra || e == sa || e == pa) ? (unsigned short)0x3F80 : (unsigned short)0;
}

// ---------------- build A_out = [h * Cct_shft, onehots] ----------------------
__global__ __launch_bounds__(128) void k_build_out(
    const int* __restrict__ rgap, const int* __restrict__ sgap, const int* __restrict__ pcount,
    const unsigned short* __restrict__ h_all, const float* __restrict__ cWT,
    unsigned short* __restrict__ A) {
    int m = blockIdx.x;
    int b = m & 127, t = m >> 7;
    int src = b * 200 + t;
    int ra = rgap[src], sa = 32 + sgap[src], pa = 64 + pcount[src];
    int e = threadIdx.x;
#pragma unroll
    for (int j = 0; j < 2; ++j) {
        int ee = e + j * 128;
        float cc = cWT[ra * 256 + ee] + cWT[sa * 256 + ee] + cWT[pa * 256 + ee];
        float v = bf2f(h_all[(long)m * 256 + ee]);
        A[(long)m * 384 + ee] = f2bf(v * cc);
    }
    A[(long)m * 384 + 256 + e] =
        (e == ra || e == sa || e == pa) ? (unsigned short)0x3F80 : (unsigned short)0;
}

// ---------------- GEMM: C[M,1024] = A[M,384](bf16) @ Bw[1024,384](bf16)^T ----
// Grid flattened to 1600 with XCD-locality mapping: bid = 64*chunk + 8*n + x,
// m = chunk*8 + x, n = (bid>>3)&7. The 8 n-blocks of one A-row-panel have
// bids congruent mod 8 -> same XCD (round-robin dispatch) -> A panel L2-hits.
// BOTH tiles staged via global_load_lds width=16 (R19-verified).
template<int EPI>
__global__ __launch_bounds__(256) void k_gemm(
    const unsigned short* __restrict__ A,
    const unsigned short* __restrict__ Bw,
    const float* __restrict__ bias,
    unsigned short* __restrict__ obf,
    float* __restrict__ of) {
    __shared__ unsigned short As[128 * 32];
    __shared__ unsigned short Bs[128 * 32];
    const int bid = blockIdx.x;
    const int m0 = (((bid >> 6) << 3) + (bid & 7)) * 128;
    const int n0 = ((bid >> 3) & 7) * 128;
    const int tid = threadIdx.x;
    const int wave = tid >> 6, lane = tid & 63;
    const int wm = wave >> 1, wn = wave & 1;
    const int n = lane & 15, q = lane >> 4;
    const int rrA = tid >> 2, ccA = (tid & 3) * 8;
    f32x4 acc[4][4] = {};
    for (int ks = 0; ks < 12; ++ks) {
        __syncthreads();
        {   // A + B tiles: async global->LDS, 4 x 16B per thread
            const unsigned short* gA = A + (long)(m0 + rrA) * 384 + ks * 32 + ccA;
            gl_lds16(gA, &As[rrA * 32 + ccA]);
            gl_lds16(gA + 64 * 384, &As[(rrA + 64) * 32 + ccA]);
            const unsigned short* gB = Bw + (long)(n0 + rrA) * 384 + ks * 32 + ccA;
            gl_lds16(gB, &Bs[rrA * 32 + ccA]);
            gl_lds16(gB + 64 * 384, &Bs[(rrA + 64) * 32 + ccA]);
        }
        __syncthreads();
        bf16x8 af[4], bfr[4];
#pragma unroll
        for (int mt = 0; mt < 4; ++mt)
            af[mt] = ld8(&As[(wm * 64 + mt * 16 + n) * 32 + q * 8]);
#pragma unroll
        for (int nt = 0; nt < 4; ++nt)
            bfr[nt] = ld8(&Bs[(wn * 64 + nt * 16 + n) * 32 + q * 8]);
#pragma unroll
        for (int mt = 0; mt < 4; ++mt)
#pragma unroll
            for (int nt = 0; nt < 4; ++nt)
                acc[mt][nt] = __builtin_amdgcn_mfma_f32_16x16x32_bf16(
                    af[mt], bfr[nt], acc[mt][nt], 0, 0, 0);
    }
#pragma unroll
    for (int mt = 0; mt < 4; ++mt) {
#pragma unroll
        for (int nt = 0; nt < 4; ++nt) {
            int col = n0 + wn * 64 + nt * 16 + n;
            float bv = bias[col];
#pragma unroll
            for (int rg = 0; rg < 4; ++rg) {
                int row = m0 + wm * 64 + mt * 16 + q * 4 + rg;
                float v = acc[mt][nt][rg] + bv;
                if (EPI == 0) {
                    obf[(long)row * 1024 + (col & 255) * 4 + (col >> 8)] = f2bf(v);
                } else {
                    int bb = row & 127, tt = row >> 7;
                    of[((long)bb * 200 + tt) * 1024 + col] = sigmoidf_(v);
                }
            }
        }
    }
}

// ---- explicit-AGPR weight residency (R9 idiom x R10 K=128 layout) -----------
#define LDW8(R0, R1, p)                                                     \
    asm volatile("global_load_dwordx4 a[" R0 "], %0, off\n\t"               \
                 "global_load_dwordx4 a[" R1 "], %0, off offset:16"         \
                 :: "v"(p) : "memory")
#define MFMA8(RR, accv, hfv)                                                \
    asm volatile("v_mfma_f32_16x16x128_f8f6f4 %0, %1, a[" RR "], %0"        \
                 : "+v"(accv) : "v"(hfv))

// ---------------- LSTM: 128 WGs x 1 batch row x 8 waves, 2 waves/SIMD --------
// EXACT R19 version (157 us, absmax 0.0039; R20's deferred store was neutral
// and doubled absmax -> reverted). K=128 fp8 MFMA, weights in explicitly
// numbered AGPRs a[0:127] loaded once by asm global_load.
__global__ __launch_bounds__(512, 2) void k_lstm(
    const unsigned short* __restrict__ xg,   // [200*128][256][4] bf16 gate-interleaved
    const unsigned char* __restrict__ Wq8,   // [1024][256] fp8 e4m3 (x16)
    unsigned short* __restrict__ h_all) {    // [200*128][256] bf16
    __shared__ __align__(32) unsigned char hb8[2][288];  // h fp8 (1 row), dbuf

    const int tid = threadIdx.x;
    const int w = tid >> 6, lane = tid & 63;
    const int n = lane & 15, q = lane >> 4;
    const int b0 = blockIdx.x;               // this WG's batch row
    const int ug = q & 1;                    // lane's unit-group within the wave

    // anchor: force agpr_count = 128 in kernel metadata
    asm volatile("" ::: "a0", "a31", "a63", "a95", "a127");

    // ---- weights: 8 tiles (tg = ug2*4+g) x 2 k-halves -> a[(tg*2+kh)*8 .. +7]
    const int cbase = w * 32 + n;
    const int qoff = q * 32;
#define WSRC(G, UG2, KH) (Wq8 + (((G) * 256 + cbase + (UG2) * 16) << 8) + (KH) * 128 + qoff)
    LDW8("0:3",     "4:7",     WSRC(0, 0, 0));
    LDW8("8:11",    "12:15",   WSRC(0, 0, 1));
    LDW8("16:19",   "20:23",   WSRC(1, 0, 0));
    LDW8("24:27",   "28:31",   WSRC(1, 0, 1));
    LDW8("32:35",   "36:39",   WSRC(2, 0, 0));
    LDW8("40:43",   "44:47",   WSRC(2, 0, 1));
    LDW8("48:51",   "52:55",   WSRC(3, 0, 0));
    LDW8("56:59",   "60:63",   WSRC(3, 0, 1));
    LDW8("64:67",   "68:71",   WSRC(0, 1, 0));
    LDW8("72:75",   "76:79",   WSRC(0, 1, 1));
    LDW8("80:83",   "84:87",   WSRC(1, 1, 0));
    LDW8("88:91",   "92:95",   WSRC(1, 1, 1));
    LDW8("96:99",   "100:103", WSRC(2, 1, 0));
    LDW8("104:107", "108:111", WSRC(2, 1, 1));
    LDW8("112:115", "116:119", WSRC(3, 1, 0));
    LDW8("120:123", "124:127", WSRC(3, 1, 1));
#undef WSRC
    asm volatile("s_waitcnt vmcnt(0)" ::: "memory");
    __builtin_amdgcn_sched_barrier(0);

    for (int i = tid; i < 288; i += 512) { hb8[0][i] = 0; hb8[1][i] = 0; }

    const int u = w * 32 + ug * 16 + n;      // this lane's hidden unit
    const unsigned short* xgp = xg + (long)b0 * 1024 + u * 4;   // += 131072 per t
    unsigned short* hap = h_all + (long)b0 * 256 + u;           // += 32768 per t
    const bool writer = (q < 2);             // one writer per unit

    float cs = 0.f;
    __syncthreads();

    for (int t = 0; t < 200; ++t) {
        const int cur = t & 1, nxt = cur ^ 1;

        // xg load issued now, consumed after the MFMA phase (latency hidden)
        uint2 xv = *(const uint2*)xgp;
        xgp += 131072;

        // h fragments: k-half 0 and 1 (row-replicated -> LDS broadcast)
        v8i hf0 = *(const v8i*)(&hb8[cur][q * 32]);
        v8i hf1 = *(const v8i*)(&hb8[cur][128 + q * 32]);

        // gates: 8 tiles x (2 x K=128), weights from explicit AGPRs
        f32x4 acc0 = {}, acc1 = {}, acc2 = {}, acc3 = {};
        f32x4 acc4 = {}, acc5 = {}, acc6 = {}, acc7 = {};
        MFMA8("0:7",     acc0, hf0); MFMA8("8:15",    acc0, hf1);
        MFMA8("16:23",   acc1, hf0); MFMA8("24:31",   acc1, hf1);
        MFMA8("32:39",   acc2, hf0); MFMA8("40:47",   acc2, hf1);
        MFMA8("48:55",   acc3, hf0); MFMA8("56:63",   acc3, hf1);
        MFMA8("64:71",   acc4, hf0); MFMA8("72:79",   acc4, hf1);
        MFMA8("80:87",   acc5, hf0); MFMA8("88:95",   acc5, hf1);
        MFMA8("96:103",  acc6, hf0); MFMA8("104:111", acc6, hf1);
        MFMA8("112:119", acc7, hf0); MFMA8("120:127", acc7, hf1);

        f32x4 vg0 = ug ? acc4 : acc0;
        f32x4 vg1 = ug ? acc5 : acc1;
        f32x4 vg2 = ug ? acc6 : acc2;
        f32x4 vg3 = ug ? acc7 : acc3;

        // ---- elementwise LSTM update (replicated rows identical -> use [0])
        const float S = 1.0f / 256.0f;  // undo x16 * x16 operand scaling (exact)
        {
            float iv = vg0[0] * S + bf2f((unsigned short)(xv.x & 0xFFFFu));
            float fv = vg1[0] * S + bf2f((unsigned short)(xv.x >> 16));
            float gg = vg2[0] * S + bf2f((unsigned short)(xv.y & 0xFFFFu));
            float ov = vg3[0] * S + bf2f((unsigned short)(xv.y >> 16));
            float cn = sigmoidf_(fv) * cs + sigmoidf_(iv) * tanhf_(gg);
            float hv = sigmoidf_(ov) * tanhf_(cn);
            cs = cn;
            if (writer) {
                hap[0] = f2bf(hv);
                unsigned p8 = __builtin_amdgcn_cvt_pk_fp8_f32(hv * 16.0f, 0.0f, 0, false);
                hb8[nxt][u] = (unsigned char)p8;
            }
        }
        hap += 32768;
        __syncthreads();
    }
}

extern "C" void kernel_launch(void* const* d_in, const int* in_sizes, int n_in,
                              void* d_out, int out_size, void* d_ws, size_t ws_size,
                              hipStream_t stream) {
    const int* c        = (const int*)d_in[0];
    const int* r        = (const int*)d_in[1];
    const int* rgap     = (const int*)d_in[2];
    const int* sgap     = (const int*)d_in[3];
    const int* pcount   = (const int*)d_in[4];
    const int* s_rgap   = (const int*)d_in[5];
    const int* s_sgap   = (const int*)d_in[6];
    const int* s_pcount = (const int*)d_in[7];
    const float* E      = (const float*)d_in[8];
    const float* cemb_W = (const float*)d_in[9];
    const float* W_ih   = (const float*)d_in[10];
    const float* W_hh   = (const float*)d_in[11];
    const float* b_ih   = (const float*)d_in[12];
    const float* b_hh   = (const float*)d_in[13];
    const float* out_W  = (const float*)d_in[14];
    const float* out_b  = (const float*)d_in[15];

    char* ws = (char*)d_ws;
    float* cWT            = (float*)(ws);                       // 131072 B
    float* bsum           = (float*)(ws + 131072);              // 4096 B
    unsigned char* Wq8    = (unsigned char*)(ws + 135168);      // 262144 B
    unsigned short* h_all = (unsigned short*)(ws + 397312);     // 13107200 B
    unsigned short* Abuf  = (unsigned short*)(ws + 13504512);   // 19660800 B
    unsigned short* xg    = (unsigned short*)(ws + 33165312);   // 52428800 B
    // aliases into DEAD regions (no ws growth):
    unsigned short* Wihb  = h_all;  // prep writes, gemm0 reads; k_lstm clobbers later
    unsigned short* Woutb = xg;     // k_conv_outw writes AFTER k_lstm (xg dead)

    k_prep<<<256, 256, 0, stream>>>(cemb_W, b_ih, b_hh, W_hh, W_ih,
                                    cWT, bsum, Wq8, Wihb);
    k_build_in<<<25600, 128, 0, stream>>>(c, r, rgap, sgap, pcount, E, cWT, Abuf);
    k_gemm<0><<<1600, 256, 0, stream>>>(Abuf, Wihb, bsum, xg, nullptr);
    k_lstm<<<128, 512, 0, stream>>>(xg, Wq8, h_all);
    k_conv_outw<<<384, 256, 0, stream>>>(out_W, Woutb);
    k_build_out<<<25600, 128, 0, stream>>>(s_rgap, s_sgap, s_pcount, h_all, cWT, Abuf);
    k_gemm<1><<<1600, 256, 0, stream>>>(Abuf, Woutb, out_b, nullptr, (float*)d_out);
}